// Round 1
// baseline (104.561 us; speedup 1.0000x reference)
//
#include <hip/hip_runtime.h>

// ---------------------------------------------------------------------------
// MalConvLowMem: B=4, T=2e6, E=8, C=128, K=512, STRIDE=512, CHUNK=64000, OVERLAP=511
// POS replay: step=63489; chunks j=0..30 give 125 positions (pos=j*63489+512*k),
// chunk 31 gives 62. P=3937 total, all distinct, none clipped.
// Window (t,e) of pos p is x[b] flat offset pos*8 + (t*8+e)  -> contiguous 4096 floats.
// => GEMM: M=4*3937=15748 rows (windows), N=256 cols (w1|w2 channels), K=4096.
// Epilogue: g=(c1+b1)*sigmoid(c2+b2); out[b][c]=max over positions.
// ---------------------------------------------------------------------------

#define T_LEN 2000000
#define P_CNT 3937
#define M_TOT 15748   // 4*3937
#define KD    4096    // K*E

typedef __attribute__((ext_vector_type(8))) short short8;   // 8 bf16 in 4 VGPRs
typedef __attribute__((ext_vector_type(4))) float f32x4;

static __device__ __forceinline__ unsigned short f2bf(float f) {
    unsigned u = __builtin_bit_cast(unsigned, f);
    unsigned r = (u + 0x7FFFu + ((u >> 16) & 1u)) >> 16;   // RNE
    return (unsigned short)r;
}

// monotone order-encoding of float for atomicMax on unsigned
static __device__ __forceinline__ unsigned ordenc(float f) {
    unsigned u = __builtin_bit_cast(unsigned, f);
    return (u & 0x80000000u) ? ~u : (u | 0x80000000u);
}

// ---------------------------------------------------------------------------
// Kernel 1: repack weights to Bp[n][k] bf16 (n<128: w1, n>=128: w2; k=t*8+e)
// and init the 512 output slots to order-encoded -inf (0u).
// ---------------------------------------------------------------------------
__global__ __launch_bounds__(256) void pack_w(const float* __restrict__ w1,
                                              const float* __restrict__ w2,
                                              unsigned short* __restrict__ Bp,
                                              unsigned* __restrict__ outu) {
    int idx = blockIdx.x * 256 + threadIdx.x;           // [0, 1048576)
    if (idx < 512) outu[idx] = 0u;                      // below any real encoding
    if (idx >= 256 * KD) return;
    int n = idx >> 12;
    int k = idx & 4095;
    int e = k & 7;
    int t = k >> 3;
    const float* src = (n < 128) ? w1 : w2;
    float v = src[(n & 127) * 4096 + e * 512 + t];
    Bp[idx] = f2bf(v);
}

// ---------------------------------------------------------------------------
// Kernel 2: fused GEMM + gate + max.
// BM=64 rows x BN=256 cols per block, BK=64, 4 waves (256 thr), 64 K-steps.
// LDS: As 64x64 bf16 (8KB, pitch 128B) | Bs 256x64 bf16 (32KB, pitch 128B);
// epilogue reuses smem as gt[64][256] f32 (64KB). XOR swizzle (row&7)<<4 on
// byte offsets kills the 128B-pitch same-bank conflict for ds_read_b128.
// ---------------------------------------------------------------------------
__global__ __launch_bounds__(256) void gemm_max(const float* __restrict__ x,
                                                const unsigned short* __restrict__ Bp,
                                                const float* __restrict__ b1,
                                                const float* __restrict__ b2,
                                                unsigned* __restrict__ outu) {
    __shared__ __align__(16) char smem[65536 + 512 + 256];
    size_t* rowoff = (size_t*)(smem + 65536);
    int*    rowb   = (int*)(smem + 65536 + 512);

    const int t  = threadIdx.x;
    const int m0 = blockIdx.x * 64;

    if (t < 64) {
        int m = m0 + t;
        if (m > M_TOT - 1) m = M_TOT - 1;     // duplicate last row in tail tile
        int bb = m / P_CNT;
        int p  = m - bb * P_CNT;
        int j, kp;
        if (p < 3875) { j = p / 125; kp = p - j * 125; }
        else          { j = 31;      kp = p - 3875; }
        long pos = (long)j * 63489 + (long)kp * 512;
        rowoff[t] = ((size_t)bb * T_LEN + (size_t)pos) * 8u;
        rowb[t]   = bb;
    }
    __syncthreads();

    const int w    = t >> 6;
    const int lane = t & 63;

    // ---- precomputed staging addresses (constant across K-steps) ----
    // A: 1024 chunks of 4 floats; chunk cid=i*256+t -> row cid>>4, kc=cid&15
    const int rA  = t >> 4;          // + 16*i
    const int kcA = t & 15;
    size_t aoff[4];
    int    awoff[4];
#pragma unroll
    for (int i = 0; i < 4; ++i) {
        int r = i * 16 + rA;
        aoff[i]  = rowoff[r] + (size_t)(kcA * 4);
        awoff[i] = (r * 128 + kcA * 8) ^ ((r & 7) << 4);
    }
    // B: 2048 chunks of 16B; cid=i*256+t -> n=cid>>3, kc=cid&7
    const int nB0 = t >> 3;          // + 32*i
    const int kcB = t & 7;
    int bgoff[8], bwoff[8];
#pragma unroll
    for (int i = 0; i < 8; ++i) {
        int n = i * 32 + nB0;
        bgoff[i] = n * KD + kcB * 8;
        bwoff[i] = (n * 128 + kcB * 16) ^ ((n & 7) << 4);
    }

    f32x4 acc[4][4];
#pragma unroll
    for (int mf = 0; mf < 4; ++mf)
#pragma unroll
        for (int nf = 0; nf < 4; ++nf)
            acc[mf][nf] = (f32x4){0.f, 0.f, 0.f, 0.f};

    for (int ks = 0; ks < KD / 64; ++ks) {
        const int kk = ks * 64;
        __syncthreads();
        // ---- stage A (fp32 -> bf16) ----
#pragma unroll
        for (int i = 0; i < 4; ++i) {
            const float4 v = *(const float4*)(x + aoff[i] + kk);
            ushort4 h;
            h.x = f2bf(v.x); h.y = f2bf(v.y); h.z = f2bf(v.z); h.w = f2bf(v.w);
            *(ushort4*)(smem + awoff[i]) = h;
        }
        // ---- stage B (pre-packed bf16) ----
#pragma unroll
        for (int i = 0; i < 8; ++i) {
            uint4 v = *(const uint4*)(Bp + bgoff[i] + kk);
            *(uint4*)(smem + 8192 + bwoff[i]) = v;
        }
        __syncthreads();
        // ---- compute ----
#pragma unroll
        for (int kq = 0; kq < 2; ++kq) {
            short8 af[4], bfr[4];
#pragma unroll
            for (int mf = 0; mf < 4; ++mf) {
                int r    = mf * 16 + (lane & 15);
                int boff = (r * 128 + kq * 64 + (lane >> 4) * 16) ^ ((r & 7) << 4);
                af[mf] = *(const short8*)(smem + boff);
            }
#pragma unroll
            for (int nf = 0; nf < 4; ++nf) {
                int n    = w * 64 + nf * 16 + (lane & 15);
                int boff = (n * 128 + kq * 64 + (lane >> 4) * 16) ^ ((n & 7) << 4);
                bfr[nf] = *(const short8*)(smem + 8192 + boff);
            }
#pragma unroll
            for (int mf = 0; mf < 4; ++mf)
#pragma unroll
                for (int nf = 0; nf < 4; ++nf)
                    acc[mf][nf] = __builtin_amdgcn_mfma_f32_16x16x32_bf16(
                        af[mf], bfr[nf], acc[mf][nf], 0, 0, 0);
        }
    }
    __syncthreads();   // done reading As/Bs; reuse smem for the f32 tile

    // ---- epilogue: spill accumulators to LDS gt[64][256] ----
    float* gt = (float*)smem;
#pragma unroll
    for (int mf = 0; mf < 4; ++mf)
#pragma unroll
        for (int nf = 0; nf < 4; ++nf) {
            int col = w * 64 + nf * 16 + (lane & 15);
#pragma unroll
            for (int q = 0; q < 4; ++q) {
                int row = mf * 16 + (lane >> 4) * 4 + q;   // C/D map: m89-verified
                gt[row * 256 + col] = acc[mf][nf][q];
            }
        }
    __syncthreads();

    // ---- gate + per-(b,c) running max + atomicMax ----
    if (t < 128) {
        const int   c   = t;
        const float bb1 = b1[c];
        const float bb2 = b2[c];
        int   bprev = rowb[0];
        float best  = -3.4e38f;
        for (int r = 0; r < 64; ++r) {
            float c1 = gt[r * 256 + c] + bb1;
            float c2 = gt[r * 256 + 128 + c] + bb2;
            float g  = c1 / (1.f + __expf(-c2));           // c1 * sigmoid(c2)
            int bb = rowb[r];
            if (bb != bprev) {
                atomicMax(&outu[bprev * 128 + c], ordenc(best));
                bprev = bb;
                best  = -3.4e38f;
            }
            best = fmaxf(best, g);
        }
        atomicMax(&outu[bprev * 128 + c], ordenc(best));
    }
}

// ---------------------------------------------------------------------------
// Kernel 3: decode order-encoded uints back to floats, in place in d_out.
// ---------------------------------------------------------------------------
__global__ __launch_bounds__(256) void unmap_out(unsigned* __restrict__ outu) {
    int i = blockIdx.x * 256 + threadIdx.x;
    if (i < 512) {
        unsigned u = outu[i];
        unsigned f = (u & 0x80000000u) ? (u ^ 0x80000000u) : ~u;
        outu[i] = f;
    }
}

extern "C" void kernel_launch(void* const* d_in, const int* in_sizes, int n_in,
                              void* d_out, int out_size, void* d_ws, size_t ws_size,
                              hipStream_t stream) {
    const float* x  = (const float*)d_in[0];
    const float* w1 = (const float*)d_in[1];
    const float* b1 = (const float*)d_in[2];
    const float* w2 = (const float*)d_in[3];
    const float* b2 = (const float*)d_in[4];

    unsigned short* Bp   = (unsigned short*)d_ws;   // 256*4096*2 = 2 MB
    unsigned*       outu = (unsigned*)d_out;        // 512 slots, order-encoded

    pack_w<<<dim3((256 * KD) / 256), dim3(256), 0, stream>>>(w1, w2, Bp, outu);

    const int nblk = (M_TOT + 63) / 64;             // 247
    gemm_max<<<dim3(nblk), dim3(256), 0, stream>>>(x, Bp, b1, b2, outu);

    unmap_out<<<dim3(2), dim3(256), 0, stream>>>(outu);
}

// Round 2
// 90.566 us; speedup vs baseline: 1.1545x; 1.1545x over previous
//
#include <hip/hip_runtime.h>

// ---------------------------------------------------------------------------
// MalConvLowMem: B=4, T=2e6, E=8, C=128, K=512, STRIDE=512
// => GEMM: M=15748 windows (4096 contiguous floats each), N=256 (w1|w2), K=4096
// Epilogue: g=(c1+b1)*sigmoid(c2+b2); out[b][c]=max over positions.
// R2: 8 waves, double-buffered LDS (80KB), B staged via global_load_lds with
// pre-inverse-swizzled source, A reg-staged (fp32->bf16 cvt) async-split.
// ---------------------------------------------------------------------------

#define T_LEN 2000000
#define P_CNT 3937
#define M_TOT 15748
#define KD    4096

typedef __attribute__((ext_vector_type(8))) short short8;
typedef __attribute__((ext_vector_type(4))) float f32x4;

static __device__ __forceinline__ unsigned short f2bf(float f) {
    unsigned u = __builtin_bit_cast(unsigned, f);
    unsigned r = (u + 0x7FFFu + ((u >> 16) & 1u)) >> 16;   // RNE
    return (unsigned short)r;
}

static __device__ __forceinline__ unsigned ordenc(float f) {
    unsigned u = __builtin_bit_cast(unsigned, f);
    return (u & 0x80000000u) ? ~u : (u | 0x80000000u);
}

#define GLD_LDS16(gp, lp)                                                      \
    __builtin_amdgcn_global_load_lds(                                          \
        (const __attribute__((address_space(1))) void*)(gp),                   \
        (__attribute__((address_space(3))) void*)(lp), 16, 0, 0)

// ---------------------------------------------------------------------------
// Kernel 1: repack weights to Bp[n][k] bf16 (n<128: w1, else w2; k=t*8+e),
// init 512 output slots to order-encoded -inf.
// ---------------------------------------------------------------------------
__global__ __launch_bounds__(256) void pack_w(const float* __restrict__ w1,
                                              const float* __restrict__ w2,
                                              unsigned short* __restrict__ Bp,
                                              unsigned* __restrict__ outu) {
    int idx = blockIdx.x * 256 + threadIdx.x;
    if (idx < 512) outu[idx] = 0u;
    if (idx >= 256 * KD) return;
    int n = idx >> 12;
    int k = idx & 4095;
    int e = k & 7;
    int t = k >> 3;
    const float* src = (n < 128) ? w1 : w2;
    Bp[idx] = f2bf(src[(n & 127) * 4096 + e * 512 + t]);
}

// ---------------------------------------------------------------------------
// Kernel 2: fused GEMM + gate + max. BM=64 x BN=256, BK=64, 512 thr (8 waves,
// 2M x 4N). LDS: As[2] 8KB @0/8192, Bs[2] 32KB @16384/49152 (80KB total),
// XOR swizzle ^((row&7)<<4). Epilogue reuses [0,64KB) as gt[64][256] f32.
// ---------------------------------------------------------------------------
__global__ __launch_bounds__(512) void gemm_max(const float* __restrict__ x,
                                                const unsigned short* __restrict__ Bp,
                                                const float* __restrict__ b1,
                                                const float* __restrict__ b2,
                                                unsigned* __restrict__ outu) {
    __shared__ __align__(16) char smem[81920 + 512 + 256];
    size_t* rowoff = (size_t*)(smem + 81920);
    int*    rowb   = (int*)(smem + 81920 + 512);

    const int t  = threadIdx.x;
    const int m0 = blockIdx.x * 64;

    if (t < 64) {
        int m = m0 + t;
        if (m > M_TOT - 1) m = M_TOT - 1;     // tail tile: duplicate last row
        int bb = m / P_CNT;
        int p  = m - bb * P_CNT;
        int j, kp;
        if (p < 3875) { j = p / 125; kp = p - j * 125; }
        else          { j = 31;      kp = p - 3875; }
        long pos = (long)j * 63489 + (long)kp * 512;
        rowoff[t] = ((size_t)bb * T_LEN + (size_t)pos) * 8u;
        rowb[t]   = bb;
    }
    __syncthreads();

    const int w    = t >> 6;      // wave 0..7
    const int lane = t & 63;
    const int wm   = w >> 2;      // 0..1
    const int wn   = w & 3;       // 0..3

    // ---- A staging (reg path, 2 x float4/thread): cid=i*512+t -> row,kc ----
    size_t aoff[2];
    int    awoff[2];
#pragma unroll
    for (int i = 0; i < 2; ++i) {
        int cid = i * 512 + t;
        int r   = cid >> 4;
        int kc  = cid & 15;
        aoff[i]  = rowoff[r] + (size_t)(kc * 4);
        awoff[i] = (r * 128 + kc * 8) ^ ((r & 7) << 4);
    }
    // ---- B staging (global_load_lds, 4 insts/thread), pre-inverse-swizzled
    // source: linear LDS dest d -> n=d>>7, kc=((d>>4)&7)^(n&7) ----
    const unsigned short* bsrc[4];
    int bdst[4];                                    // wave-uniform LDS offset
#pragma unroll
    for (int i = 0; i < 4; ++i) {
        int d  = i * 8192 + w * 1024 + lane * 16;   // linear dest in B buffer
        int n  = d >> 7;
        int kc = ((d >> 4) & 7) ^ (n & 7);
        bsrc[i] = Bp + n * KD + kc * 8;
        bdst[i] = i * 8192 + w * 1024;              // + lane*16 done by HW
    }

    f32x4 acc[2][4];
#pragma unroll
    for (int mf = 0; mf < 2; ++mf)
#pragma unroll
        for (int nf = 0; nf < 4; ++nf)
            acc[mf][nf] = (f32x4){0.f, 0.f, 0.f, 0.f};

    // ---- prologue: stage tile 0 into buf 0 ----
    {
        float4 a0[2];
#pragma unroll
        for (int i = 0; i < 2; ++i) a0[i] = *(const float4*)(x + aoff[i]);
#pragma unroll
        for (int i = 0; i < 4; ++i) GLD_LDS16(bsrc[i], smem + 16384 + bdst[i]);
#pragma unroll
        for (int i = 0; i < 2; ++i) {
            ushort4 h;
            h.x = f2bf(a0[i].x); h.y = f2bf(a0[i].y);
            h.z = f2bf(a0[i].z); h.w = f2bf(a0[i].w);
            *(ushort4*)(smem + awoff[i]) = h;
        }
    }
    __syncthreads();

    for (int ks = 0; ks < 64; ++ks) {
        const int cur = ks & 1;
        const int As  = cur * 8192;
        const int Bs  = 16384 + cur * 32768;
        float4 an[2];
        if (ks < 63) {
            const int kk = (ks + 1) * 64;
            // issue next-tile loads early: A->regs, B->LDS (async)
#pragma unroll
            for (int i = 0; i < 2; ++i) an[i] = *(const float4*)(x + aoff[i] + kk);
            const int Bsn = 16384 + (cur ^ 1) * 32768;
#pragma unroll
            for (int i = 0; i < 4; ++i) GLD_LDS16(bsrc[i] + kk, smem + Bsn + bdst[i]);
        }
        // ---- compute from buf[cur] ----
#pragma unroll
        for (int kq = 0; kq < 2; ++kq) {
            short8 af[2], bfr[4];
#pragma unroll
            for (int mf = 0; mf < 2; ++mf) {
                int r    = wm * 32 + mf * 16 + (lane & 15);
                int boff = (r * 128 + kq * 64 + (lane >> 4) * 16) ^ ((r & 7) << 4);
                af[mf] = *(const short8*)(smem + As + boff);
            }
#pragma unroll
            for (int nf = 0; nf < 4; ++nf) {
                int n    = wn * 64 + nf * 16 + (lane & 15);
                int boff = (n * 128 + kq * 64 + (lane >> 4) * 16) ^ ((n & 7) << 4);
                bfr[nf] = *(const short8*)(smem + Bs + boff);
            }
#pragma unroll
            for (int mf = 0; mf < 2; ++mf)
#pragma unroll
                for (int nf = 0; nf < 4; ++nf)
                    acc[mf][nf] = __builtin_amdgcn_mfma_f32_16x16x32_bf16(
                        af[mf], bfr[nf], acc[mf][nf], 0, 0, 0);
        }
        // ---- write A for next tile into buf[cur^1] ----
        if (ks < 63) {
            const int Asn = (cur ^ 1) * 8192;
#pragma unroll
            for (int i = 0; i < 2; ++i) {
                ushort4 h;
                h.x = f2bf(an[i].x); h.y = f2bf(an[i].y);
                h.z = f2bf(an[i].z); h.w = f2bf(an[i].w);
                *(ushort4*)(smem + Asn + awoff[i]) = h;
            }
        }
        __syncthreads();
    }

    // ---- epilogue: spill acc to gt[64][256] f32 (reuses staging LDS) ----
    float* gt = (float*)smem;
#pragma unroll
    for (int mf = 0; mf < 2; ++mf)
#pragma unroll
        for (int nf = 0; nf < 4; ++nf) {
            int col = wn * 64 + nf * 16 + (lane & 15);
#pragma unroll
            for (int q = 0; q < 4; ++q) {
                int row = wm * 32 + mf * 16 + (lane >> 4) * 4 + q;
                gt[row * 256 + col] = acc[mf][nf][q];
            }
        }
    __syncthreads();

    // ---- gate + per-(b,c) running max + atomicMax ----
    if (t < 128) {
        const int   c   = t;
        const float bb1 = b1[c];
        const float bb2 = b2[c];
        int   bprev = rowb[0];
        float best  = -3.4e38f;
        for (int r = 0; r < 64; ++r) {
            float c1 = gt[r * 256 + c] + bb1;
            float c2 = gt[r * 256 + 128 + c] + bb2;
            float g  = c1 / (1.f + __expf(-c2));
            int bb = rowb[r];
            if (bb != bprev) {
                atomicMax(&outu[bprev * 128 + c], ordenc(best));
                bprev = bb;
                best  = -3.4e38f;
            }
            best = fmaxf(best, g);
        }
        atomicMax(&outu[bprev * 128 + c], ordenc(best));
    }
}

// ---------------------------------------------------------------------------
// Kernel 3: decode order-encoded uints to floats in place.
// ---------------------------------------------------------------------------
__global__ __launch_bounds__(256) void unmap_out(unsigned* __restrict__ outu) {
    int i = blockIdx.x * 256 + threadIdx.x;
    if (i < 512) {
        unsigned u = outu[i];
        outu[i] = (u & 0x80000000u) ? (u ^ 0x80000000u) : ~u;
    }
}

extern "C" void kernel_launch(void* const* d_in, const int* in_sizes, int n_in,
                              void* d_out, int out_size, void* d_ws, size_t ws_size,
                              hipStream_t stream) {
    const float* x  = (const float*)d_in[0];
    const float* w1 = (const float*)d_in[1];
    const float* b1 = (const float*)d_in[2];
    const float* w2 = (const float*)d_in[3];
    const float* b2 = (const float*)d_in[4];

    unsigned short* Bp   = (unsigned short*)d_ws;   // 2 MB packed bf16 weights
    unsigned*       outu = (unsigned*)d_out;

    pack_w<<<dim3((256 * KD) / 256), dim3(256), 0, stream>>>(w1, w2, Bp, outu);

    const int nblk = (M_TOT + 63) / 64;             // 247
    gemm_max<<<dim3(nblk), dim3(512), 0, stream>>>(x, Bp, b1, b2, outu);

    unmap_out<<<dim3(2), dim3(256), 0, stream>>>(outu);
}

// Round 3
// 84.607 us; speedup vs baseline: 1.2358x; 1.0704x over previous
//
#include <hip/hip_runtime.h>

// ---------------------------------------------------------------------------
// MalConvLowMem: GEMM M=15748 (windows, 4096 contiguous floats each),
// N=256 (w1|w2 channels), K=4096; epilogue gate+max.
// R3: BM=32, grid=493, LDS=72KB -> 2 blocks/CU (16 waves/CU) so one block's
// barrier drain overlaps the other's compute. Row offsets computed per-thread
// (no rowoff LDS). Double-buffered As/Bs, B via global_load_lds w/ pre-inverse
// swizzled source, A reg-staged fp32->bf16.
// ---------------------------------------------------------------------------

#define T_LEN 2000000
#define P_CNT 3937
#define M_TOT 15748
#define KD    4096

typedef __attribute__((ext_vector_type(8))) short short8;
typedef __attribute__((ext_vector_type(4))) float f32x4;

static __device__ __forceinline__ unsigned short f2bf(float f) {
    unsigned u = __builtin_bit_cast(unsigned, f);
    unsigned r = (u + 0x7FFFu + ((u >> 16) & 1u)) >> 16;   // RNE
    return (unsigned short)r;
}

static __device__ __forceinline__ unsigned ordenc(float f) {
    unsigned u = __builtin_bit_cast(unsigned, f);
    return (u & 0x80000000u) ? ~u : (u | 0x80000000u);
}

// row m (clamped) -> flat float offset of window start in x
static __device__ __forceinline__ size_t row_base(int m) {
    if (m > M_TOT - 1) m = M_TOT - 1;
    int bb = m / P_CNT;
    int p  = m - bb * P_CNT;
    int j, kp;
    if (p < 3875) { j = p / 125; kp = p - j * 125; }
    else          { j = 31;      kp = p - 3875; }
    long pos = (long)j * 63489 + (long)kp * 512;
    return ((size_t)bb * T_LEN + (size_t)pos) * 8u;
}

#define GLD_LDS16(gp, lp)                                                      \
    __builtin_amdgcn_global_load_lds(                                          \
        (const __attribute__((address_space(1))) void*)(gp),                   \
        (__attribute__((address_space(3))) void*)(lp), 16, 0, 0)

// ---------------------------------------------------------------------------
// Kernel 1: repack weights to Bp[n][k] bf16 (n<128: w1, else w2; k=t*8+e),
// init 512 output slots to order-encoded -inf.
// ---------------------------------------------------------------------------
__global__ __launch_bounds__(256) void pack_w(const float* __restrict__ w1,
                                              const float* __restrict__ w2,
                                              unsigned short* __restrict__ Bp,
                                              unsigned* __restrict__ outu) {
    int idx = blockIdx.x * 256 + threadIdx.x;
    if (idx < 512) outu[idx] = 0u;
    if (idx >= 256 * KD) return;
    int n = idx >> 12;
    int k = idx & 4095;
    int e = k & 7;
    int t = k >> 3;
    const float* src = (n < 128) ? w1 : w2;
    Bp[idx] = f2bf(src[(n & 127) * 4096 + e * 512 + t]);
}

// ---------------------------------------------------------------------------
// Kernel 2: fused GEMM + gate + max. BM=32 x BN=256, BK=64, 512 thr (8 waves:
// 2M x 4N, each wave 16x64). LDS: As[2] 4KB @0/4096, Bs[2] 32KB @8192/40960
// (72KB total -> 2 blocks/CU). XOR swizzle ^((row&7)<<4).
// Epilogue reuses [0,32KB) as gt[32][256] f32.
// ---------------------------------------------------------------------------
__global__ __launch_bounds__(512, 4) void gemm_max(const float* __restrict__ x,
                                                   const unsigned short* __restrict__ Bp,
                                                   const float* __restrict__ b1,
                                                   const float* __restrict__ b2,
                                                   unsigned* __restrict__ outu) {
    __shared__ __align__(16) char smem[73728];

    const int t  = threadIdx.x;
    const int m0 = blockIdx.x * 32;

    const int w    = t >> 6;      // wave 0..7
    const int lane = t & 63;
    const int wm   = w >> 2;      // 0..1 (16 rows each)
    const int wn   = w & 3;       // 0..3 (64 cols each)

    // ---- A staging: 1 chunk (float4) per thread: r=t>>4, kc=t&15 ----
    const int rA  = t >> 4;       // 0..31
    const int kcA = t & 15;
    const size_t aoff  = row_base(m0 + rA) + (size_t)(kcA * 4);
    const int    awoff = (rA * 128 + kcA * 8) ^ ((rA & 7) << 4);

    // ---- B staging (global_load_lds, 4/thread), pre-inverse-swizzled src:
    // linear dest d -> n=d>>7, kc=((d>>4)&7)^(n&7) ----
    const unsigned short* bsrc[4];
    int bdst[4];
#pragma unroll
    for (int i = 0; i < 4; ++i) {
        int d  = i * 8192 + w * 1024 + lane * 16;
        int n  = d >> 7;
        int kc = ((d >> 4) & 7) ^ (n & 7);
        bsrc[i] = Bp + n * KD + kc * 8;
        bdst[i] = i * 8192 + w * 1024;              // + lane*16 by HW
    }

    f32x4 acc[4];
#pragma unroll
    for (int nf = 0; nf < 4; ++nf) acc[nf] = (f32x4){0.f, 0.f, 0.f, 0.f};

    // ---- prologue: stage tile 0 into buf 0 ----
    {
        float4 a0 = *(const float4*)(x + aoff);
#pragma unroll
        for (int i = 0; i < 4; ++i) GLD_LDS16(bsrc[i], smem + 8192 + bdst[i]);
        ushort4 h;
        h.x = f2bf(a0.x); h.y = f2bf(a0.y); h.z = f2bf(a0.z); h.w = f2bf(a0.w);
        *(ushort4*)(smem + awoff) = h;
    }
    __syncthreads();

    for (int ks = 0; ks < 64; ++ks) {
        const int cur = ks & 1;
        const int As  = cur * 4096;
        const int Bs  = 8192 + cur * 32768;
        float4 an;
        if (ks < 63) {
            const int kk = (ks + 1) * 64;
            an = *(const float4*)(x + aoff + kk);
            const int Bsn = 8192 + (cur ^ 1) * 32768;
#pragma unroll
            for (int i = 0; i < 4; ++i) GLD_LDS16(bsrc[i] + kk, smem + Bsn + bdst[i]);
        }
        // ---- compute from buf[cur] ----
#pragma unroll
        for (int kq = 0; kq < 2; ++kq) {
            short8 af, bfr[4];
            {
                int r    = wm * 16 + (lane & 15);
                int boff = (r * 128 + kq * 64 + (lane >> 4) * 16) ^ ((r & 7) << 4);
                af = *(const short8*)(smem + As + boff);
            }
#pragma unroll
            for (int nf = 0; nf < 4; ++nf) {
                int n    = wn * 64 + nf * 16 + (lane & 15);
                int boff = (n * 128 + kq * 64 + (lane >> 4) * 16) ^ ((n & 7) << 4);
                bfr[nf] = *(const short8*)(smem + Bs + boff);
            }
#pragma unroll
            for (int nf = 0; nf < 4; ++nf)
                acc[nf] = __builtin_amdgcn_mfma_f32_16x16x32_bf16(
                    af, bfr[nf], acc[nf], 0, 0, 0);
        }
        // ---- write next A tile into buf[cur^1] ----
        if (ks < 63) {
            const int Asn = (cur ^ 1) * 4096;
            ushort4 h;
            h.x = f2bf(an.x); h.y = f2bf(an.y); h.z = f2bf(an.z); h.w = f2bf(an.w);
            *(ushort4*)(smem + Asn + awoff) = h;
        }
        __syncthreads();
    }

    // ---- epilogue: spill acc to gt[32][256] f32 ----
    float* gt = (float*)smem;
#pragma unroll
    for (int nf = 0; nf < 4; ++nf) {
        int col = wn * 64 + nf * 16 + (lane & 15);
#pragma unroll
        for (int q = 0; q < 4; ++q) {
            int row = wm * 16 + (lane >> 4) * 4 + q;
            gt[row * 256 + col] = acc[nf][q];
        }
    }
    __syncthreads();

    // ---- gate + per-(b,c) running max + atomicMax ----
    if (t < 128) {
        const int   c   = t;
        const float bb1 = b1[c];
        const float bb2 = b2[c];
        int   bprev = (m0 < M_TOT ? m0 : M_TOT - 1) / P_CNT;
        float best  = -3.4e38f;
        for (int r = 0; r < 32; ++r) {
            int m = m0 + r;
            if (m > M_TOT - 1) m = M_TOT - 1;
            int bb = m / P_CNT;
            float c1 = gt[r * 256 + c] + bb1;
            float c2 = gt[r * 256 + 128 + c] + bb2;
            float g  = c1 / (1.f + __expf(-c2));
            if (bb != bprev) {
                atomicMax(&outu[bprev * 128 + c], ordenc(best));
                bprev = bb;
                best  = -3.4e38f;
            }
            best = fmaxf(best, g);
        }
        atomicMax(&outu[bprev * 128 + c], ordenc(best));
    }
}

// ---------------------------------------------------------------------------
// Kernel 3: decode order-encoded uints to floats in place.
// ---------------------------------------------------------------------------
__global__ __launch_bounds__(256) void unmap_out(unsigned* __restrict__ outu) {
    int i = blockIdx.x * 256 + threadIdx.x;
    if (i < 512) {
        unsigned u = outu[i];
        outu[i] = (u & 0x80000000u) ? (u ^ 0x80000000u) : ~u;
    }
}

extern "C" void kernel_launch(void* const* d_in, const int* in_sizes, int n_in,
                              void* d_out, int out_size, void* d_ws, size_t ws_size,
                              hipStream_t stream) {
    const float* x  = (const float*)d_in[0];
    const float* w1 = (const float*)d_in[1];
    const float* b1 = (const float*)d_in[2];
    const float* w2 = (const float*)d_in[3];
    const float* b2 = (const float*)d_in[4];

    unsigned short* Bp   = (unsigned short*)d_ws;   // 2 MB packed bf16 weights
    unsigned*       outu = (unsigned*)d_out;

    pack_w<<<dim3((256 * KD) / 256), dim3(256), 0, stream>>>(w1, w2, Bp, outu);

    const int nblk = (M_TOT + 31) / 32;             // 493
    gemm_max<<<dim3(nblk), dim3(512), 0, stream>>>(x, Bp, b1, b2, outu);

    unmap_out<<<dim3(2), dim3(256), 0, stream>>>(outu);
}